// Round 20
// baseline (209.100 us; speedup 1.0000x reference)
//
#include <hip/hip_runtime.h>
#include <hip/hip_bf16.h>

// Problem constants (reference: B,S,H,D = 2,2048,32,128)
constexpr int Bc = 2;
constexpr int Sc = 2048;
constexpr int Hc = 32;
constexpr int Dc = 128;
constexpr int QKV_STRIDE = 3 * Hc * Dc;   // floats per (b, s) row: 12288

constexpr int BQ = 128;  // query rows per block (4 waves x 32 rows)
constexpr int BK = 64;   // kv rows per tile
// scale (1/sqrt(128)) * log2(e), folded into Q at load; softmax in base-2
constexpr float SCALE_LOG2E = 0.088388347648318f * 1.442695040888963f;
constexpr float DEFER_THR = 8.0f;   // T13

// LDS strides (shorts) — measured conflict-free (r4-r19: SQ_LDS_BANK_CONFLICT = 0)
constexpr int KST = 132;   // K row 264B
constexpr int VST = 68;    // V row 136B

typedef __attribute__((ext_vector_type(8)))  short    bf16x8;
typedef __attribute__((ext_vector_type(4)))  short    bf16x4;
typedef __attribute__((ext_vector_type(16))) float    f32x16;
typedef __attribute__((ext_vector_type(4)))  unsigned u32x4;

static __device__ __forceinline__ short f2bf(float f) {
    __bf16 h = (__bf16)f;                  // RNE; compiler pairs into v_cvt_pk_bf16_f32
    return __builtin_bit_cast(short, h);
}
static __device__ __forceinline__ unsigned pk2(float lo, float hi) {
    union { short2 s; unsigned u; } x;
    x.s.x = f2bf(lo); x.s.y = f2bf(hi);
    return x.u;
}
// v_permlane32_swap_b32 (verified r12): after plswap(dst, src):
//   new_dst = [dst_lo, src_lo], new_src = [dst_hi, src_hi]
// NOTE: operands must hold DIFFERENT values (equal operands may coalesce -> no-op).
static __device__ __forceinline__ void plswap(unsigned& dst, unsigned& src) {
    asm volatile("v_permlane32_swap_b32 %0, %1" : "+v"(dst), "+v"(src));
}
// Raw barrier (lgkm drain only) — next-tile global loads stay in flight across it.
static __device__ __forceinline__ void lds_barrier() {
    asm volatile("s_waitcnt lgkmcnt(0)" ::: "memory");
    __builtin_amdgcn_s_barrier();
    asm volatile("" ::: "memory");
}

__global__ __launch_bounds__(256)
void attn_fwd(const float* __restrict__ qkv,
              const int* __restrict__ causal_p,
              float* __restrict__ out)
{
    // Work-balanced 1D grid (r7, measured +37%): bid = o*64 + bh; o -> qt such
    // that co-resident classes {o,o+4,o+8,o+12} have equal total causal work.
    const int bid = blockIdx.x;
    const int o   = bid >> 6;
    const int bh  = bid & 63;
    const int r_  = o & 3;
    const int j_  = o >> 2;
    const int bq_ = 15 - 2 * r_;
    const int qt  = (j_ < 2) ? (bq_ - j_) : (15 - bq_ + 3 - j_);

    const int b = bh >> 5;    // H = 32
    const int h = bh & 31;
    const int causal = *causal_p;

    const int tid  = threadIdx.x;
    const int w    = tid >> 6;     // wave 0..3, owns 32 q rows
    const int lane = tid & 63;
    const int l31  = lane & 31;
    const int hf   = lane >> 5;    // half 0/1

    __shared__ short Ks[64 * KST];    // K tile [k][d]
    __shared__ short Vs[128 * VST];   // V tile transposed [d][k]

    const int q0  = qt * BQ;
    const int wq0 = q0 + w * 32;      // wave's first global q row

    // staging decomposition: 8 k-row groups x 32 d-lanes
    const int kg = tid >> 5;   // 0..7 -> k rows kg*8 .. kg*8+7
    const int dl = tid & 31;

    const float* kplane = qkv + (size_t)b * Sc * QKV_STRIDE + Hc * Dc + h * Dc;

    // ---- Q as swapped-QK B-fragments: lane holds q = l31, dh = st*16 + hf*8 + j ----
    bf16x8 qf[8];
    {
        const float* qb = qkv + (size_t)(b * Sc + wq0 + l31) * QKV_STRIDE + h * Dc;
        #pragma unroll
        for (int st = 0; st < 8; ++st) {
            const float* p = qb + st * 16 + hf * 8;
            float4 x0 = *(const float4*)(p);
            float4 x1 = *(const float4*)(p + 4);
            bf16x8 q;
            q[0] = f2bf(x0.x * SCALE_LOG2E);
            q[1] = f2bf(x0.y * SCALE_LOG2E);
            q[2] = f2bf(x0.z * SCALE_LOG2E);
            q[3] = f2bf(x0.w * SCALE_LOG2E);
            q[4] = f2bf(x1.x * SCALE_LOG2E);
            q[5] = f2bf(x1.y * SCALE_LOG2E);
            q[6] = f2bf(x1.z * SCALE_LOG2E);
            q[7] = f2bf(x1.w * SCALE_LOG2E);
            qf[st] = q;
        }
    }

    f32x16 o_[4];
    #pragma unroll
    for (int db = 0; db < 4; ++db)
        #pragma unroll
        for (int i = 0; i < 16; ++i) o_[db][i] = 0.f;
    float m = -1e30f, l = 0.f;

    const int nkv = causal ? (2 * qt + 2) : (Sc / BK);

    // ---- staging registers ----
    // fp32 in-flight loads (tile t+1), converted bf16 forms (written next commit).
    // Live ranges don't overlap: kbf/vbf die at commit; kst/vst born at issue after.
    float4 kst[8];
    float  vst[8][4];
    bf16x4 kbf[8];
    bf16x8 vbf[4];

    auto issue = [&](int kt) {
        const float* kb = kplane + (size_t)(kt * BK + kg * 8) * QKV_STRIDE;
        #pragma unroll
        for (int j = 0; j < 8; ++j)
            kst[j] = *(const float4*)(kb + (size_t)j * QKV_STRIDE + dl * 4);
        const float* vb = kb + Hc * Dc;
        #pragma unroll
        for (int j = 0; j < 8; ++j) {
            #pragma unroll
            for (int q = 0; q < 4; ++q)
                vst[j][q] = vb[(size_t)j * QKV_STRIDE + q * 32 + dl];
        }
    };

    // fp32 -> bf16, runs at END of compute phase (loads long landed); frees the
    // inter-barrier region of ~96 VALU convert ops.
    auto convert = [&]() {
        #pragma unroll
        for (int j = 0; j < 8; ++j) {
            bf16x4 kk;
            kk[0] = f2bf(kst[j].x); kk[1] = f2bf(kst[j].y);
            kk[2] = f2bf(kst[j].z); kk[3] = f2bf(kst[j].w);
            kbf[j] = kk;
        }
        #pragma unroll
        for (int q = 0; q < 4; ++q) {
            bf16x8 vv;
            #pragma unroll
            for (int j = 0; j < 8; ++j) vv[j] = f2bf(vst[j][q]);
            vbf[q] = vv;
        }
    };

    // pure ds_writes — the only work left between the barriers
    auto commit = [&]() {
        #pragma unroll
        for (int j = 0; j < 8; ++j)
            *(bf16x4*)&Ks[(kg * 8 + j) * KST + dl * 4] = kbf[j];
        #pragma unroll
        for (int q = 0; q < 4; ++q)
            *(bf16x8*)&Vs[(q * 32 + dl) * VST + kg * 8] = vbf[q];
    };

    issue(0);
    convert();   // waits on tile-0 loads (prologue only)

    for (int kt = 0; kt < nkv; ++kt) {
        lds_barrier();                      // prev tile's readers done
        commit();                           // pure writes (no cvt, no load-wait)
        if (kt + 1 < nkv) issue(kt + 1);    // flies across the raw barrier
        lds_barrier();                      // staged tile visible

        const int kbase = kt * BK;
        const bool active = !(causal && kbase > wq0 + 31);   // wave-uniform

        if (active) {
            // ---- S^T = K Q^T : lane holds S[q=l31][32 k's per mb via C-layout] ----
            f32x16 acc[2];
            #pragma unroll
            for (int mb = 0; mb < 2; ++mb)
                #pragma unroll
                for (int i = 0; i < 16; ++i) acc[mb][i] = 0.f;
            __builtin_amdgcn_s_setprio(1);
            #pragma unroll
            for (int st = 0; st < 8; ++st) {
                #pragma unroll
                for (int mb = 0; mb < 2; ++mb) {
                    bf16x8 ka = *(const bf16x8*)&Ks[(mb * 32 + l31) * KST + st * 16 + hf * 8];
                    acc[mb] = __builtin_amdgcn_mfma_f32_32x32x16_bf16(ka, qf[st], acc[mb], 0, 0, 0);
                }
            }
            __builtin_amdgcn_s_setprio(0);

            // ---- causal mask (straddle tiles only) ----
            if (causal && kbase + 63 > wq0) {
                const int qg = wq0 + l31;
                #pragma unroll
                for (int mb = 0; mb < 2; ++mb) {
                    #pragma unroll
                    for (int r = 0; r < 16; ++r) {
                        const int kgl = kbase + mb * 32 + (r & 3) + 8 * (r >> 2) + 4 * hf;
                        if (kgl > qg) acc[mb][r] = -1e30f;
                    }
                }
            }

            // ---- online softmax: in-lane chain + __shfl_xor cross-half; T13 ----
            float pm = acc[0][0];
            #pragma unroll
            for (int i = 1; i < 16; ++i) pm = fmaxf(pm, acc[0][i]);
            #pragma unroll
            for (int i = 0; i < 16; ++i) pm = fmaxf(pm, acc[1][i]);
            pm = fmaxf(pm, __shfl_xor(pm, 32));
            if (__any(pm > m + DEFER_THR)) {
                const float mnew  = fmaxf(m, pm);
                const float alpha = __builtin_amdgcn_exp2f(m - mnew);
                m = mnew; l *= alpha;
                #pragma unroll
                for (int r = 0; r < 16; ++r) {
                    const float ar = __shfl(alpha, (r & 3) + 8 * (r >> 2) + 4 * hf);
                    o_[0][r] *= ar; o_[1][r] *= ar; o_[2][r] *= ar; o_[3][r] *= ar;
                }
            }
            float rs = 0.f;
            #pragma unroll
            for (int i = 0; i < 16; ++i) {
                const float p = __builtin_amdgcn_exp2f(acc[0][i] - m);
                acc[0][i] = p; rs += p;
            }
            #pragma unroll
            for (int i = 0; i < 16; ++i) {
                const float p = __builtin_amdgcn_exp2f(acc[1][i] - m);
                acc[1][i] = p; rs += p;
            }
            rs += __shfl_xor(rs, 32);
            l += rs;

            // ---- P -> bf16 A-fragments: 16 cvt_pk + 8 permlane swaps (verified r12) ----
            unsigned wpk[2][4][2];
            #pragma unroll
            for (int mb = 0; mb < 2; ++mb)
                #pragma unroll
                for (int c = 0; c < 4; ++c) {
                    wpk[mb][c][0] = pk2(acc[mb][4 * c + 0], acc[mb][4 * c + 1]);
                    wpk[mb][c][1] = pk2(acc[mb][4 * c + 2], acc[mb][4 * c + 3]);
                }
            bf16x8 pa[4];
            #pragma unroll
            for (int ks = 0; ks < 4; ++ks) {
                const int mb = ks >> 1, ci = ks & 1;
                unsigned e0 = wpk[mb][2 * ci][0], o0 = wpk[mb][2 * ci + 1][0];
                unsigned e1 = wpk[mb][2 * ci][1], o1 = wpk[mb][2 * ci + 1][1];
                plswap(e0, o0);   // dst = even group, src = odd group
                plswap(e1, o1);
                u32x4 wv;
                wv[0] = e0; wv[1] = e1; wv[2] = o0; wv[3] = o1;
                pa[ks] = __builtin_bit_cast(bf16x8, wv);
            }

            // ---- O += P V  (4 independent accumulator chains) ----
            __builtin_amdgcn_s_setprio(1);
            #pragma unroll
            for (int ks = 0; ks < 4; ++ks) {
                #pragma unroll
                for (int db = 0; db < 4; ++db) {
                    bf16x8 vb = *(const bf16x8*)&Vs[(db * 32 + l31) * VST + ks * 16 + hf * 8];
                    o_[db] = __builtin_amdgcn_mfma_f32_32x32x16_bf16(pa[ks], vb, o_[db], 0, 0, 0);
                }
            }
            __builtin_amdgcn_s_setprio(0);
        }

        // convert tile kt+1's staged fp32 -> bf16 (EVERY wave, even compute-skipped
        // ones: commit feeds block-shared LDS). Loads have had the whole compute
        // phase to land; waits here are short.
        if (kt + 1 < nkv) convert();
    }

    // ---- epilogue: per-row 1/l gather + fp32 store (lanes contiguous in d) ----
    #pragma unroll
    for (int r = 0; r < 16; ++r) {
        const int rq = (r & 3) + 8 * (r >> 2) + 4 * hf;
        const float lr = __shfl(l, rq);
        const float inv = 1.f / lr;
        const int qg = wq0 + rq;
        float* ob = out + (size_t)(b * Sc + qg) * (Hc * Dc) + h * Dc + l31;
        ob[0]  = o_[0][r] * inv;
        ob[32] = o_[1][r] * inv;
        ob[64] = o_[2][r] * inv;
        ob[96] = o_[3][r] * inv;
    }
}

extern "C" void kernel_launch(void* const* d_in, const int* in_sizes, int n_in,
                              void* d_out, int out_size, void* d_ws, size_t ws_size,
                              hipStream_t stream) {
    const float* qkv = (const float*)d_in[0];
    const int* causal = (const int*)d_in[1];
    float* out = (float*)d_out;
    dim3 grid((Sc / BQ) * Bc * Hc);   // 1024, balanced 1D mapping
    attn_fwd<<<grid, 256, 0, stream>>>(qkv, causal, out);
}

// Round 21
// 199.860 us; speedup vs baseline: 1.0462x; 1.0462x over previous
//
#include <hip/hip_runtime.h>
#include <hip/hip_bf16.h>

// Problem constants (reference: B,S,H,D = 2,2048,32,128)
constexpr int Bc = 2;
constexpr int Sc = 2048;
constexpr int Hc = 32;
constexpr int Dc = 128;
constexpr int QKV_STRIDE = 3 * Hc * Dc;   // floats per (b, s) row: 12288

constexpr int BQ = 128;  // query rows per tile-pass (4 waves x 32 rows)
constexpr int BK = 64;   // kv rows per tile
// scale (1/sqrt(128)) * log2(e), folded into Q at load; softmax in base-2
constexpr float SCALE_LOG2E = 0.088388347648318f * 1.442695040888963f;
constexpr float DEFER_THR = 8.0f;   // T13

// LDS strides (shorts) — measured conflict-free (r4-r20: SQ_LDS_BANK_CONFLICT = 0)
constexpr int KST = 132;   // K row 264B
constexpr int VST = 68;    // V row 136B

typedef __attribute__((ext_vector_type(8)))  short    bf16x8;
typedef __attribute__((ext_vector_type(4)))  short    bf16x4;
typedef __attribute__((ext_vector_type(16))) float    f32x16;
typedef __attribute__((ext_vector_type(4)))  unsigned u32x4;

static __device__ __forceinline__ short f2bf(float f) {
    __bf16 h = (__bf16)f;                  // RNE; compiler pairs into v_cvt_pk_bf16_f32
    return __builtin_bit_cast(short, h);
}
static __device__ __forceinline__ unsigned pk2(float lo, float hi) {
    union { short2 s; unsigned u; } x;
    x.s.x = f2bf(lo); x.s.y = f2bf(hi);
    return x.u;
}
// v_permlane32_swap_b32 (verified r12): after plswap(dst, src):
//   new_dst = [dst_lo, src_lo], new_src = [dst_hi, src_hi]
// NOTE: operands must hold DIFFERENT values (equal operands may coalesce -> no-op).
static __device__ __forceinline__ void plswap(unsigned& dst, unsigned& src) {
    asm volatile("v_permlane32_swap_b32 %0, %1" : "+v"(dst), "+v"(src));
}
// Raw barrier (lgkm drain only) — next-tile global loads stay in flight across it.
static __device__ __forceinline__ void lds_barrier() {
    asm volatile("s_waitcnt lgkmcnt(0)" ::: "memory");
    __builtin_amdgcn_s_barrier();
    asm volatile("" ::: "memory");
}

__global__ __launch_bounds__(256)
void attn_fwd(const float* __restrict__ qkv,
              const int* __restrict__ causal_p,
              float* __restrict__ out)
{
    // UNIFORM-WORK pairing (r21): block p handles Q-tiles {15-p, p}. Causal work
    // per block = (2(15-p)+2) + (2p+2) = 36 tiles for EVERY block -> grid 512
    // = exactly 256 CUs x 2 resident blocks (VGPR 168 -> 2 waves/SIMD), one
    // dispatch round, no tail, no backfill; balancing table unnecessary.
    const int bid = blockIdx.x;
    const int p   = bid >> 6;     // 0..7
    const int bh  = bid & 63;

    const int b = bh >> 5;    // H = 32
    const int h = bh & 31;
    const int causal = *causal_p;

    const int tid  = threadIdx.x;
    const int w    = tid >> 6;     // wave 0..3, owns 32 q rows
    const int lane = tid & 63;
    const int l31  = lane & 31;
    const int hf   = lane >> 5;    // half 0/1

    __shared__ short Ks[64 * KST];    // K tile [k][d]
    __shared__ short Vs[128 * VST];   // V tile transposed [d][k]

    // staging decomposition: 8 k-row groups x 32 d-lanes
    const int kg = tid >> 5;   // 0..7 -> k rows kg*8 .. kg*8+7
    const int dl = tid & 31;

    const float* kplane = qkv + (size_t)b * Sc * QKV_STRIDE + Hc * Dc + h * Dc;

    // ---- staging registers (tile t+1 in flight during compute of t) ----
    float4 kst[8];
    float  vst[8][4];

    auto issue = [&](int kt) {
        const float* kb = kplane + (size_t)(kt * BK + kg * 8) * QKV_STRIDE;
        #pragma unroll
        for (int j = 0; j < 8; ++j)
            kst[j] = *(const float4*)(kb + (size_t)j * QKV_STRIDE + dl * 4);
        const float* vb = kb + Hc * Dc;
        #pragma unroll
        for (int j = 0; j < 8; ++j) {
            #pragma unroll
            for (int q = 0; q < 4; ++q)
                vst[j][q] = vb[(size_t)j * QKV_STRIDE + q * 32 + dl];
        }
    };

    auto commit = [&]() {
        #pragma unroll
        for (int j = 0; j < 8; ++j) {
            bf16x4 kk;
            kk[0] = f2bf(kst[j].x); kk[1] = f2bf(kst[j].y);
            kk[2] = f2bf(kst[j].z); kk[3] = f2bf(kst[j].w);
            *(bf16x4*)&Ks[(kg * 8 + j) * KST + dl * 4] = kk;
        }
        #pragma unroll
        for (int q = 0; q < 4; ++q) {
            bf16x8 vv;
            #pragma unroll
            for (int j = 0; j < 8; ++j) vv[j] = f2bf(vst[j][q]);
            *(bf16x8*)&Vs[(q * 32 + dl) * VST + kg * 8] = vv;
        }
    };

    // ---- two Q-tile passes per block: qt = 15-p then p (uniform total work) ----
    #pragma unroll 1
    for (int hx = 0; hx < 2; ++hx) {
        const int qt  = hx ? p : (15 - p);
        const int q0  = qt * BQ;
        const int wq0 = q0 + w * 32;      // wave's first global q row

        // ---- Q as swapped-QK B-fragments: lane holds q=l31, dh = st*16+hf*8+j ----
        bf16x8 qf[8];
        {
            const float* qb = qkv + (size_t)(b * Sc + wq0 + l31) * QKV_STRIDE + h * Dc;
            #pragma unroll
            for (int st = 0; st < 8; ++st) {
                const float* pq = qb + st * 16 + hf * 8;
                float4 x0 = *(const float4*)(pq);
                float4 x1 = *(const float4*)(pq + 4);
                bf16x8 q;
                q[0] = f2bf(x0.x * SCALE_LOG2E);
                q[1] = f2bf(x0.y * SCALE_LOG2E);
                q[2] = f2bf(x0.z * SCALE_LOG2E);
                q[3] = f2bf(x0.w * SCALE_LOG2E);
                q[4] = f2bf(x1.x * SCALE_LOG2E);
                q[5] = f2bf(x1.y * SCALE_LOG2E);
                q[6] = f2bf(x1.z * SCALE_LOG2E);
                q[7] = f2bf(x1.w * SCALE_LOG2E);
                qf[st] = q;
            }
        }

        f32x16 o_[4];
        #pragma unroll
        for (int db = 0; db < 4; ++db)
            #pragma unroll
            for (int i = 0; i < 16; ++i) o_[db][i] = 0.f;
        float m = -1e30f, l = 0.f;

        const int nkv = causal ? (2 * qt + 2) : (Sc / BK);

        issue(0);

        for (int kt = 0; kt < nkv; ++kt) {
            lds_barrier();                      // prev tile's readers done
            commit();
            if (kt + 1 < nkv) issue(kt + 1);    // flies across the raw barrier
            lds_barrier();                      // staged tile visible

            const int kbase = kt * BK;
            if (causal && kbase > wq0 + 31) continue;   // per-wave skip (no barriers below)

            // ---- S^T = K Q^T : lane holds S[q=l31][32 k's per mb via C-layout] ----
            f32x16 acc[2];
            #pragma unroll
            for (int mb = 0; mb < 2; ++mb)
                #pragma unroll
                for (int i = 0; i < 16; ++i) acc[mb][i] = 0.f;
            __builtin_amdgcn_s_setprio(1);
            #pragma unroll
            for (int st = 0; st < 8; ++st) {
                #pragma unroll
                for (int mb = 0; mb < 2; ++mb) {
                    bf16x8 ka = *(const bf16x8*)&Ks[(mb * 32 + l31) * KST + st * 16 + hf * 8];
                    acc[mb] = __builtin_amdgcn_mfma_f32_32x32x16_bf16(ka, qf[st], acc[mb], 0, 0, 0);
                }
            }
            __builtin_amdgcn_s_setprio(0);

            // ---- causal mask (straddle tiles only) ----
            if (causal && kbase + 63 > wq0) {
                const int qg = wq0 + l31;
                #pragma unroll
                for (int mb = 0; mb < 2; ++mb) {
                    #pragma unroll
                    for (int r = 0; r < 16; ++r) {
                        const int kgl = kbase + mb * 32 + (r & 3) + 8 * (r >> 2) + 4 * hf;
                        if (kgl > qg) acc[mb][r] = -1e30f;
                    }
                }
            }

            // ---- online softmax: in-lane chain + __shfl_xor cross-half; T13 ----
            float pm = acc[0][0];
            #pragma unroll
            for (int i = 1; i < 16; ++i) pm = fmaxf(pm, acc[0][i]);
            #pragma unroll
            for (int i = 0; i < 16; ++i) pm = fmaxf(pm, acc[1][i]);
            pm = fmaxf(pm, __shfl_xor(pm, 32));
            if (__any(pm > m + DEFER_THR)) {
                const float mnew  = fmaxf(m, pm);
                const float alpha = __builtin_amdgcn_exp2f(m - mnew);
                m = mnew; l *= alpha;
                #pragma unroll
                for (int r = 0; r < 16; ++r) {
                    const float ar = __shfl(alpha, (r & 3) + 8 * (r >> 2) + 4 * hf);
                    o_[0][r] *= ar; o_[1][r] *= ar; o_[2][r] *= ar; o_[3][r] *= ar;
                }
            }
            float rs = 0.f;
            #pragma unroll
            for (int i = 0; i < 16; ++i) {
                const float pe = __builtin_amdgcn_exp2f(acc[0][i] - m);
                acc[0][i] = pe; rs += pe;
            }
            #pragma unroll
            for (int i = 0; i < 16; ++i) {
                const float pe = __builtin_amdgcn_exp2f(acc[1][i] - m);
                acc[1][i] = pe; rs += pe;
            }
            rs += __shfl_xor(rs, 32);
            l += rs;

            // ---- P -> bf16 A-fragments: 16 cvt_pk + 8 permlane swaps (verified r12) ----
            unsigned wpk[2][4][2];
            #pragma unroll
            for (int mb = 0; mb < 2; ++mb)
                #pragma unroll
                for (int c = 0; c < 4; ++c) {
                    wpk[mb][c][0] = pk2(acc[mb][4 * c + 0], acc[mb][4 * c + 1]);
                    wpk[mb][c][1] = pk2(acc[mb][4 * c + 2], acc[mb][4 * c + 3]);
                }
            bf16x8 pa[4];
            #pragma unroll
            for (int ks = 0; ks < 4; ++ks) {
                const int mb = ks >> 1, ci = ks & 1;
                unsigned e0 = wpk[mb][2 * ci][0], o0 = wpk[mb][2 * ci + 1][0];
                unsigned e1 = wpk[mb][2 * ci][1], o1 = wpk[mb][2 * ci + 1][1];
                plswap(e0, o0);   // dst = even group, src = odd group
                plswap(e1, o1);
                u32x4 wv;
                wv[0] = e0; wv[1] = e1; wv[2] = o0; wv[3] = o1;
                pa[ks] = __builtin_bit_cast(bf16x8, wv);
            }

            // ---- O += P V  (4 independent accumulator chains) ----
            __builtin_amdgcn_s_setprio(1);
            #pragma unroll
            for (int ks = 0; ks < 4; ++ks) {
                #pragma unroll
                for (int db = 0; db < 4; ++db) {
                    bf16x8 vb = *(const bf16x8*)&Vs[(db * 32 + l31) * VST + ks * 16 + hf * 8];
                    o_[db] = __builtin_amdgcn_mfma_f32_32x32x16_bf16(pa[ks], vb, o_[db], 0, 0, 0);
                }
            }
            __builtin_amdgcn_s_setprio(0);
        }

        // ---- epilogue: per-row 1/l gather + fp32 store (lanes contiguous in d) ----
        #pragma unroll
        for (int r = 0; r < 16; ++r) {
            const int rq = (r & 3) + 8 * (r >> 2) + 4 * hf;
            const float lr = __shfl(l, rq);
            const float inv = 1.f / lr;
            const int qg = wq0 + rq;
            float* ob = out + (size_t)(b * Sc + qg) * (Hc * Dc) + h * Dc + l31;
            ob[0]  = o_[0][r] * inv;
            ob[32] = o_[1][r] * inv;
            ob[64] = o_[2][r] * inv;
            ob[96] = o_[3][r] * inv;
        }
    }
}

extern "C" void kernel_launch(void* const* d_in, const int* in_sizes, int n_in,
                              void* d_out, int out_size, void* d_ws, size_t ws_size,
                              hipStream_t stream) {
    const float* qkv = (const float*)d_in[0];
    const int* causal = (const int*)d_in[1];
    float* out = (float*)d_out;
    dim3 grid((Sc / BQ) / 2 * Bc * Hc);   // 512 uniform-work blocks (2 Q-tiles each)
    attn_fwd<<<grid, 256, 0, stream>>>(qkv, causal, out);
}

// Round 22
// 196.719 us; speedup vs baseline: 1.0629x; 1.0160x over previous
//
#include <hip/hip_runtime.h>
#include <hip/hip_bf16.h>

// Problem constants (reference: B,S,H,D = 2,2048,32,128)
constexpr int Bc = 2;
constexpr int Sc = 2048;
constexpr int Hc = 32;
constexpr int Dc = 128;
constexpr int QKV_STRIDE = 3 * Hc * Dc;   // floats per (b, s) row: 12288

constexpr int BQ = 128;  // query rows per block (4 waves x 32 rows)
constexpr int BK = 64;   // kv rows per tile
// scale (1/sqrt(128)) * log2(e), folded into Q at load; softmax in base-2
constexpr float SCALE_LOG2E = 0.088388347648318f * 1.442695040888963f;
constexpr float DEFER_THR = 8.0f;   // T13

// LDS strides (shorts) — measured conflict-free (r4-r21: SQ_LDS_BANK_CONFLICT = 0)
constexpr int KST = 132;   // K row 264B
constexpr int VST = 68;    // V row 136B

typedef __attribute__((ext_vector_type(8)))  short    bf16x8;
typedef __attribute__((ext_vector_type(4)))  short    bf16x4;
typedef __attribute__((ext_vector_type(16))) float    f32x16;
typedef __attribute__((ext_vector_type(4)))  unsigned u32x4;

static __device__ __forceinline__ short f2bf(float f) {
    __bf16 h = (__bf16)f;                  // RNE; compiler pairs into v_cvt_pk_bf16_f32
    return __builtin_bit_cast(short, h);
}
static __device__ __forceinline__ unsigned pk2(float lo, float hi) {
    union { short2 s; unsigned u; } x;
    x.s.x = f2bf(lo); x.s.y = f2bf(hi);
    return x.u;
}
// v_permlane32_swap_b32 (verified r12): after plswap(dst, src):
//   new_dst = [dst_lo, src_lo], new_src = [dst_hi, src_hi]
// NOTE: operands must hold DIFFERENT values (equal operands may coalesce -> no-op).
static __device__ __forceinline__ void plswap(unsigned& dst, unsigned& src) {
    asm volatile("v_permlane32_swap_b32 %0, %1" : "+v"(dst), "+v"(src));
}
// Raw barrier (lgkm drain only) — next-tile global loads stay in flight across it.
static __device__ __forceinline__ void lds_barrier() {
    asm volatile("s_waitcnt lgkmcnt(0)" ::: "memory");
    __builtin_amdgcn_s_barrier();
    asm volatile("" ::: "memory");
}

__global__ __launch_bounds__(256)
void attn_fwd(const float* __restrict__ qkv,
              const int* __restrict__ causal_p,
              float* __restrict__ out)
{
    // Work-balanced 1D grid (r7, measured +37%): bid = o*64 + bh; o -> qt such
    // that co-resident classes {o,o+4,o+8,o+12} have equal total causal work.
    const int bid = blockIdx.x;
    const int o   = bid >> 6;
    const int bh  = bid & 63;
    const int r_  = o & 3;
    const int j_  = o >> 2;
    const int bq_ = 15 - 2 * r_;
    const int qt  = (j_ < 2) ? (bq_ - j_) : (15 - bq_ + 3 - j_);

    const int b = bh >> 5;    // H = 32
    const int h = bh & 31;
    const int causal = *causal_p;

    const int tid  = threadIdx.x;
    const int w    = tid >> 6;     // wave 0..3, owns 32 q rows
    const int lane = tid & 63;
    const int l31  = lane & 31;
    const int hf   = lane >> 5;    // half 0/1

    __shared__ short Ks[64 * KST];    // K tile [k][d]
    __shared__ short Vs[128 * VST];   // V tile transposed [d][k]

    const int q0  = qt * BQ;
    const int wq0 = q0 + w * 32;      // wave's first global q row

    // staging decomposition: 8 k-row groups x 32 d-lanes
    const int kg = tid >> 5;   // 0..7 -> k rows kg*8 .. kg*8+7
    const int dl = tid & 31;

    const float* kplane = qkv + (size_t)b * Sc * QKV_STRIDE + Hc * Dc + h * Dc;

    // ---- Q as swapped-QK B-fragments: lane holds q = l31, dh = st*16 + hf*8 + j ----
    bf16x8 qf[8];
    {
        const float* qb = qkv + (size_t)(b * Sc + wq0 + l31) * QKV_STRIDE + h * Dc;
        #pragma unroll
        for (int st = 0; st < 8; ++st) {
            const float* p = qb + st * 16 + hf * 8;
            float4 x0 = *(const float4*)(p);
            float4 x1 = *(const float4*)(p + 4);
            bf16x8 q;
            q[0] = f2bf(x0.x * SCALE_LOG2E);
            q[1] = f2bf(x0.y * SCALE_LOG2E);
            q[2] = f2bf(x0.z * SCALE_LOG2E);
            q[3] = f2bf(x0.w * SCALE_LOG2E);
            q[4] = f2bf(x1.x * SCALE_LOG2E);
            q[5] = f2bf(x1.y * SCALE_LOG2E);
            q[6] = f2bf(x1.z * SCALE_LOG2E);
            q[7] = f2bf(x1.w * SCALE_LOG2E);
            qf[st] = q;
        }
    }

    f32x16 o_[4];
    #pragma unroll
    for (int db = 0; db < 4; ++db)
        #pragma unroll
        for (int i = 0; i < 16; ++i) o_[db][i] = 0.f;
    float m = -1e30f, l = 0.f;

    const int nkv = causal ? (2 * qt + 2) : (Sc / BK);

    // ---- staging registers (tile t+1 in flight during compute of t) ----
    float4 kst[8];
    float  vst[8][4];

    auto issue = [&](int kt) {
        const float* kb = kplane + (size_t)(kt * BK + kg * 8) * QKV_STRIDE;
        #pragma unroll
        for (int j = 0; j < 8; ++j)
            kst[j] = *(const float4*)(kb + (size_t)j * QKV_STRIDE + dl * 4);
        const float* vb = kb + Hc * Dc;
        #pragma unroll
        for (int j = 0; j < 8; ++j) {
            #pragma unroll
            for (int q = 0; q < 4; ++q)
                vst[j][q] = vb[(size_t)j * QKV_STRIDE + q * 32 + dl];
        }
    };

    auto commit = [&]() {
        #pragma unroll
        for (int j = 0; j < 8; ++j) {
            bf16x4 kk;
            kk[0] = f2bf(kst[j].x); kk[1] = f2bf(kst[j].y);
            kk[2] = f2bf(kst[j].z); kk[3] = f2bf(kst[j].w);
            *(bf16x4*)&Ks[(kg * 8 + j) * KST + dl * 4] = kk;
        }
        #pragma unroll
        for (int q = 0; q < 4; ++q) {
            bf16x8 vv;
            #pragma unroll
            for (int j = 0; j < 8; ++j) vv[j] = f2bf(vst[j][q]);
            *(bf16x8*)&Vs[(q * 32 + dl) * VST + kg * 8] = vv;
        }
    };

    issue(0);

    for (int kt = 0; kt < nkv; ++kt) {
        lds_barrier();                      // prev tile's readers done
        commit();
        if (kt + 1 < nkv) issue(kt + 1);    // flies across the raw barrier
        lds_barrier();                      // staged tile visible

        const int kbase = kt * BK;
        if (causal && kbase > wq0 + 31) continue;   // wave-uniform skip

        // ---- S^T = K Q^T : lane holds S[q=l31][32 k's per mb via C-layout] ----
        f32x16 acc[2];
        #pragma unroll
        for (int mb = 0; mb < 2; ++mb)
            #pragma unroll
            for (int i = 0; i < 16; ++i) acc[mb][i] = 0.f;
        __builtin_amdgcn_s_setprio(1);
        #pragma unroll
        for (int st = 0; st < 8; ++st) {
            #pragma unroll
            for (int mb = 0; mb < 2; ++mb) {
                bf16x8 ka = *(const bf16x8*)&Ks[(mb * 32 + l31) * KST + st * 16 + hf * 8];
                acc[mb] = __builtin_amdgcn_mfma_f32_32x32x16_bf16(ka, qf[st], acc[mb], 0, 0, 0);
            }
        }
        __builtin_amdgcn_s_setprio(0);

        // ---- causal mask (straddle tiles only); k = kbase+mb*32+rowpat(reg,hf) ----
        if (causal && kbase + 63 > wq0) {
            const int qg = wq0 + l31;
            #pragma unroll
            for (int mb = 0; mb < 2; ++mb) {
                #pragma unroll
                for (int r = 0; r < 16; ++r) {
                    const int kgl = kbase + mb * 32 + (r & 3) + 8 * (r >> 2) + 4 * hf;
                    if (kgl > qg) acc[mb][r] = -1e30f;
                }
            }
        }

        // ---- online softmax: in-lane chain + __shfl_xor cross-half; T13 ----
        float pm = acc[0][0];
        #pragma unroll
        for (int i = 1; i < 16; ++i) pm = fmaxf(pm, acc[0][i]);
        #pragma unroll
        for (int i = 0; i < 16; ++i) pm = fmaxf(pm, acc[1][i]);
        pm = fmaxf(pm, __shfl_xor(pm, 32));
        if (__any(pm > m + DEFER_THR)) {
            const float mnew  = fmaxf(m, pm);
            const float alpha = __builtin_amdgcn_exp2f(m - mnew);
            m = mnew; l *= alpha;
            #pragma unroll
            for (int r = 0; r < 16; ++r) {
                const float ar = __shfl(alpha, (r & 3) + 8 * (r >> 2) + 4 * hf);
                o_[0][r] *= ar; o_[1][r] *= ar; o_[2][r] *= ar; o_[3][r] *= ar;
            }
        }
        float rs = 0.f;
        #pragma unroll
        for (int i = 0; i < 16; ++i) {
            const float p = __builtin_amdgcn_exp2f(acc[0][i] - m);
            acc[0][i] = p; rs += p;
        }
        #pragma unroll
        for (int i = 0; i < 16; ++i) {
            const float p = __builtin_amdgcn_exp2f(acc[1][i] - m);
            acc[1][i] = p; rs += p;
        }
        rs += __shfl_xor(rs, 32);
        l += rs;

        // ---- P -> bf16 A-fragments: 16 cvt_pk + 8 permlane swaps (verified r12).
        // swap(E=group 2ci word, O=group 2ci+1 word):
        //   E' = [E_lo, O_lo] -> fragment words j={0,1}/{2,3} for both halves
        //   O' = [E_hi, O_hi] -> fragment words j={4,5}/{6,7} for both halves
        unsigned wpk[2][4][2];
        #pragma unroll
        for (int mb = 0; mb < 2; ++mb)
            #pragma unroll
            for (int c = 0; c < 4; ++c) {
                wpk[mb][c][0] = pk2(acc[mb][4 * c + 0], acc[mb][4 * c + 1]);
                wpk[mb][c][1] = pk2(acc[mb][4 * c + 2], acc[mb][4 * c + 3]);
            }
        bf16x8 pa[4];
        #pragma unroll
        for (int ks = 0; ks < 4; ++ks) {
            const int mb = ks >> 1, ci = ks & 1;
            unsigned e0 = wpk[mb][2 * ci][0], o0 = wpk[mb][2 * ci + 1][0];
            unsigned e1 = wpk[mb][2 * ci][1], o1 = wpk[mb][2 * ci + 1][1];
            plswap(e0, o0);   // dst = even group, src = odd group
            plswap(e1, o1);
            u32x4 wv;
            wv[0] = e0; wv[1] = e1; wv[2] = o0; wv[3] = o1;
            pa[ks] = __builtin_bit_cast(bf16x8, wv);
        }

        // ---- O += P V  (4 independent accumulator chains) ----
        __builtin_amdgcn_s_setprio(1);
        #pragma unroll
        for (int ks = 0; ks < 4; ++ks) {
            #pragma unroll
            for (int db = 0; db < 4; ++db) {
                bf16x8 vb = *(const bf16x8*)&Vs[(db * 32 + l31) * VST + ks * 16 + hf * 8];
                o_[db] = __builtin_amdgcn_mfma_f32_32x32x16_bf16(pa[ks], vb, o_[db], 0, 0, 0);
            }
        }
        __builtin_amdgcn_s_setprio(0);
    }

    // ---- epilogue: per-row 1/l gather + fp32 store (lanes contiguous in d) ----
    #pragma unroll
    for (int r = 0; r < 16; ++r) {
        const int rq = (r & 3) + 8 * (r >> 2) + 4 * hf;
        const float lr = __shfl(l, rq);
        const float inv = 1.f / lr;
        const int qg = wq0 + rq;
        float* ob = out + (size_t)(b * Sc + qg) * (Hc * Dc) + h * Dc + l31;
        ob[0]  = o_[0][r] * inv;
        ob[32] = o_[1][r] * inv;
        ob[64] = o_[2][r] * inv;
        ob[96] = o_[3][r] * inv;
    }
}

extern "C" void kernel_launch(void* const* d_in, const int* in_sizes, int n_in,
                              void* d_out, int out_size, void* d_ws, size_t ws_size,
                              hipStream_t stream) {
    const float* qkv = (const float*)d_in[0];
    const int* causal = (const int*)d_in[1];
    float* out = (float*)d_out;
    dim3 grid((Sc / BQ) * Bc * Hc);   // 1024, balanced 1D mapping
    attn_fwd<<<grid, 256, 0, stream>>>(qkv, causal, out);
}